// Round 7
// baseline (304.767 us; speedup 1.0000x reference)
//
#include <hip/hip_runtime.h>
#include <math.h>

#define D     512
#define KCB   1024
#define NT2   512
#define RB    64          // latent rows per block
#define ALPHA 10.0f
#define TAU   0.008f
#define PSTR  1040        // pool row stride in us (bf16) units

typedef __attribute__((ext_vector_type(8))) short short8v;
typedef __attribute__((ext_vector_type(4))) float f32x4;
typedef unsigned short us;

__device__ __forceinline__ float wave_reduce_sum(float v) {
    #pragma unroll
    for (int off = 32; off >= 1; off >>= 1) v += __shfl_xor(v, off, 64);
    return v;
}

// fp32 -> bf16 round-to-nearest-even
__device__ __forceinline__ short bf16r(float x) {
    union { float f; unsigned u; } c; c.f = x;
    unsigned r = (c.u + 0x7FFFu + ((c.u >> 16) & 1u)) >> 16;
    return (short)r;
}

// ---- device-scope global barrier primitives (all blocks resident: grid == 256 == #CUs,
// LDS ~147 KB/block forces 1 block/CU). Monotonic counters, memset-zeroed each call.
__device__ __forceinline__ void gbar_arrive(int* c) {
    __syncthreads();
    if (threadIdx.x == 0) {
        __threadfence();
        __hip_atomic_fetch_add(c, 1, __ATOMIC_RELEASE, __HIP_MEMORY_SCOPE_AGENT);
    }
}
__device__ __forceinline__ void gbar_wait(int* c, int tgt) {
    if (threadIdx.x == 0) {
        while (__hip_atomic_load(c, __ATOMIC_ACQUIRE, __HIP_MEMORY_SCOPE_AGENT) < tgt)
            __builtin_amdgcn_s_sleep(4);
        __threadfence();
    }
    __syncthreads();
}

// ---------------- K: everything in one persistent kernel.
// Stage P (blocks 0..63): prep cb (normalized, fragment-major) + embT (raw, fragment-major) + cbinv.
//   cb   element (k,d) -> (((k>>4)*16 + (d>>5))*64 + ((d>>3)&3)*16 + (k&15))*8 + (d&7)
//   embT element (d,k) -> (((d>>4)*32 + (k>>5))*64 + ((k>>3)&3)*16 + (d&15))*8 + (k&7)
// Stage F (all blocks): attention + softmax + rescue-argmax + stats + quant GEMM + SSE (r6 logic).
// Stage R1 (blocks 0..15): reduce avg partials. Stage R2 (block 0): scalars.
__global__ __launch_bounds__(NT2, 2) void k_all(
    const float* __restrict__ lat, const float* __restrict__ emb,
    us* __restrict__ cb, us* __restrict__ embT, float* __restrict__ cbinv,
    float* __restrict__ avg_ws, float* __restrict__ scal,
    float* __restrict__ part_ws, float* __restrict__ red_ws, int use_part,
    float* __restrict__ q_out, float* __restrict__ soft_out,
    float* __restrict__ argm_out, float* __restrict__ hq_out,
    float* __restrict__ out_vq, float* __restrict__ out_ent, float* __restrict__ out_cm,
    float invB, float invBD, int nblk)
{
    extern __shared__ __align__(16) us pool[];   // [RB][PSTR]; stage P uses first 32 KB as tiles
    __shared__ float s_inv[RB];
    __shared__ float s_maxp[8][RB];
    __shared__ float s_amax[RB];
    __shared__ float s_sump[8][RB];
    __shared__ float s_den[RB];
    __shared__ float s_bestv[RB];
    __shared__ int   s_besti[RB];
    __shared__ int   s_cnt;
    __shared__ int   s_ck[1024];
    __shared__ float s_cv[1024];
    __shared__ float part[8];

    const int t = threadIdx.x, wv = t >> 6, lane = t & 63;
    const int q15 = lane & 15, g = lane >> 4;
    const int bid = blockIdx.x;
    const int b0 = bid * RB;

    float* sse_ws = scal;
    float* clu_ws = scal + 1;
    int*   ctr    = (int*)(scal + 2);      // [0],[1],[2] barrier counters

    // ================= Stage P: prep (blocks 0..63, 16 codebook rows each) =================
    if (bid < 64) {
        us* tileN = pool;                  // [16][512] normalized bf16
        us* tileR = pool + 16 * 512;       // [16][512] raw bf16
        const int kg = bid;
        #pragma unroll
        for (int rr = 0; rr < 2; ++rr) {
            const int kk = wv * 2 + rr;
            const int k = kg * 16 + kk;
            const float4* ep = (const float4*)(emb + (size_t)k * D);
            float4 a = ep[2 * lane], b = ep[2 * lane + 1];
            float ss = a.x*a.x + a.y*a.y + a.z*a.z + a.w*a.w
                     + b.x*b.x + b.y*b.y + b.z*b.z + b.w*b.w;
            ss = wave_reduce_sum(ss);
            float inv = 1.0f / fmaxf(sqrtf(ss), 1e-12f);
            short8v wn, wr;
            wn[0] = bf16r(a.x * inv); wn[1] = bf16r(a.y * inv);
            wn[2] = bf16r(a.z * inv); wn[3] = bf16r(a.w * inv);
            wn[4] = bf16r(b.x * inv); wn[5] = bf16r(b.y * inv);
            wn[6] = bf16r(b.z * inv); wn[7] = bf16r(b.w * inv);
            wr[0] = bf16r(a.x); wr[1] = bf16r(a.y); wr[2] = bf16r(a.z); wr[3] = bf16r(a.w);
            wr[4] = bf16r(b.x); wr[5] = bf16r(b.y); wr[6] = bf16r(b.z); wr[7] = bf16r(b.w);
            *(short8v*)&tileN[(size_t)kk * 512 + lane * 8] = wn;
            *(short8v*)&tileR[(size_t)kk * 512 + lane * 8] = wr;
            if (lane == 0) cbinv[k] = inv;
        }
        __syncthreads();
        // cb: 1024 16B chunks, fully coalesced
        #pragma unroll
        for (int u = 0; u < 2; ++u) {
            int ch = t + u * NT2;
            int k15 = ch & 15, j4 = (ch >> 4) & 3, c = ch >> 6;
            short8v w = *(short8v*)&tileN[(size_t)k15 * 512 + c * 32 + j4 * 8];
            *(short8v*)(cb + (size_t)kg * 8192 + (size_t)ch * 8) = w;
        }
        // embT: 1024 16B chunks, coalesced stores (strided LDS gather source)
        const int kc = kg >> 1, khalf = kg & 1;
        #pragma unroll
        for (int u = 0; u < 2; ++u) {
            int ch = t + u * NT2;
            int dc = ch >> 5, cc = ch & 31, hb = cc >> 4, dl = cc & 15;
            int dd = dc * 16 + dl;
            short8v w;
            #pragma unroll
            for (int j = 0; j < 8; ++j) w[j] = (short)tileR[(size_t)(hb * 8 + j) * 512 + dd];
            *(short8v*)(embT + ((size_t)(dc * 32 + kc)) * 512 + khalf * 256 + (size_t)cc * 8) = w;
        }
    }
    gbar_arrive(&ctr[0]);
    gbar_wait(&ctr[0], nblk);

    // ================= Stage F =================
    // ---- Phase A: normalize RB rows (8 per wave), bf16 into pool
    float4 ra[8], rb[8];
    #pragma unroll
    for (int i = 0; i < 8; ++i) {
        const float4* lp = (const float4*)(lat + (size_t)(b0 + wv * 8 + i) * D);
        ra[i] = lp[2 * lane]; rb[i] = lp[2 * lane + 1];
    }
    #pragma unroll
    for (int i = 0; i < 8; ++i) {
        int r = wv * 8 + i;
        float4 a = ra[i], b = rb[i];
        float ss = a.x*a.x + a.y*a.y + a.z*a.z + a.w*a.w
                 + b.x*b.x + b.y*b.y + b.z*b.z + b.w*b.w;
        ss = wave_reduce_sum(ss);
        float inv = 1.0f / fmaxf(sqrtf(ss), 1e-12f);
        short8v w;
        w[0] = bf16r(a.x * inv); w[1] = bf16r(a.y * inv);
        w[2] = bf16r(a.z * inv); w[3] = bf16r(a.w * inv);
        w[4] = bf16r(b.x * inv); w[5] = bf16r(b.y * inv);
        w[6] = bf16r(b.z * inv); w[7] = bf16r(b.w * inv);
        *(short8v*)&pool[(size_t)r * PSTR + lane * 8] = w;
        if (lane == 0) s_inv[r] = inv;
    }
    if (t == 0) s_cnt = 0;
    __syncthreads();

    // ---- Phase B: attention MFMA, software-pipelined B loads
    f32x4 acc[4][8];
    #pragma unroll
    for (int m = 0; m < 4; ++m)
        #pragma unroll
        for (int ct = 0; ct < 8; ++ct) { f32x4 z = {0.f, 0.f, 0.f, 0.f}; acc[m][ct] = z; }

    const us* pBw = cb + (size_t)(wv * 8) * 16 * 512 + (size_t)lane * 8;
    #define LDB_A(ks, ct) (*(const short8v*)(pBw + (size_t)((ct) * 16 + (ks)) * 512))
    #define LDA_A(row, ks) (*(const short8v*)&pool[(size_t)(row) * PSTR + (ks) * 32 + g * 8])

    short8v bE[8], bO[8];
    #pragma unroll
    for (int ct = 0; ct < 8; ++ct) bE[ct] = LDB_A(0, ct);
    for (int ks = 0; ks < 16; ks += 2) {
        #pragma unroll
        for (int ct = 0; ct < 8; ++ct) bO[ct] = LDB_A(ks + 1, ct);
        {
            short8v af0 = LDA_A(q15, ks), af1 = LDA_A(16 + q15, ks);
            short8v af2 = LDA_A(32 + q15, ks), af3 = LDA_A(48 + q15, ks);
            #pragma unroll
            for (int ct = 0; ct < 8; ++ct) {
                acc[0][ct] = __builtin_amdgcn_mfma_f32_16x16x32_bf16(af0, bE[ct], acc[0][ct], 0, 0, 0);
                acc[1][ct] = __builtin_amdgcn_mfma_f32_16x16x32_bf16(af1, bE[ct], acc[1][ct], 0, 0, 0);
                acc[2][ct] = __builtin_amdgcn_mfma_f32_16x16x32_bf16(af2, bE[ct], acc[2][ct], 0, 0, 0);
                acc[3][ct] = __builtin_amdgcn_mfma_f32_16x16x32_bf16(af3, bE[ct], acc[3][ct], 0, 0, 0);
            }
        }
        const int ksn = (ks + 2 < 16) ? ks + 2 : 0;
        #pragma unroll
        for (int ct = 0; ct < 8; ++ct) bE[ct] = LDB_A(ksn, ct);
        {
            short8v af0 = LDA_A(q15, ks + 1), af1 = LDA_A(16 + q15, ks + 1);
            short8v af2 = LDA_A(32 + q15, ks + 1), af3 = LDA_A(48 + q15, ks + 1);
            #pragma unroll
            for (int ct = 0; ct < 8; ++ct) {
                acc[0][ct] = __builtin_amdgcn_mfma_f32_16x16x32_bf16(af0, bO[ct], acc[0][ct], 0, 0, 0);
                acc[1][ct] = __builtin_amdgcn_mfma_f32_16x16x32_bf16(af1, bO[ct], acc[1][ct], 0, 0, 0);
                acc[2][ct] = __builtin_amdgcn_mfma_f32_16x16x32_bf16(af2, bO[ct], acc[2][ct], 0, 0, 0);
                acc[3][ct] = __builtin_amdgcn_mfma_f32_16x16x32_bf16(af3, bO[ct], acc[3][ct], 0, 0, 0);
            }
        }
    }

    // ---- Phase C: approx row max
    #pragma unroll
    for (int m = 0; m < 4; ++m)
        #pragma unroll
        for (int i = 0; i < 4; ++i) {
            float v = acc[m][0][i];
            #pragma unroll
            for (int ct = 1; ct < 8; ++ct) v = fmaxf(v, acc[m][ct][i]);
            #pragma unroll
            for (int off = 8; off >= 1; off >>= 1) v = fmaxf(v, __shfl_xor(v, off, 64));
            if (q15 == 0) s_maxp[wv][m * 16 + g * 4 + i] = v;
        }
    __syncthreads();
    if (t < RB) {
        float v = s_maxp[0][t];
        #pragma unroll
        for (int w = 1; w < 8; ++w) v = fmaxf(v, s_maxp[w][t]);
        s_amax[t] = v;
    }
    __syncthreads();

    // ---- Phase C2: candidate gather
    #pragma unroll
    for (int m = 0; m < 4; ++m)
        #pragma unroll
        for (int i = 0; i < 4; ++i) {
            const int row = m * 16 + g * 4 + i;
            const float thr = s_amax[row] - TAU;
            #pragma unroll
            for (int ct = 0; ct < 8; ++ct) {
                if (acc[m][ct][i] >= thr) {
                    int idx = atomicAdd(&s_cnt, 1);
                    if (idx < 1024) s_ck[idx] = (row << 16) | (wv * 128 + ct * 16 + q15);
                }
            }
        }
    __syncthreads();
    const int cnt = (s_cnt < 1024) ? s_cnt : 1024;

    // ---- Phase C3: fp32 rescue
    for (int e = wv; e < cnt; e += 8) {
        const int pk = s_ck[e];
        const int row = pk >> 16, kk = pk & 0xFFFF;
        const float4* lp = (const float4*)(lat + (size_t)(b0 + row) * D);
        const float4* ep = (const float4*)(emb + (size_t)kk * D);
        float4 x0 = lp[2 * lane], x1 = lp[2 * lane + 1];
        float4 y0 = ep[2 * lane], y1 = ep[2 * lane + 1];
        float dp = x0.x*y0.x + x0.y*y0.y + x0.z*y0.z + x0.w*y0.w
                 + x1.x*y1.x + x1.y*y1.y + x1.z*y1.z + x1.w*y1.w;
        dp = wave_reduce_sum(dp);
        if (lane == 0) s_cv[e] = dp * s_inv[row] * cbinv[kk];
    }
    __syncthreads();
    if (t < RB) {
        float bv = -1e30f; int bi = 0x7FFFFFFF;
        for (int e = 0; e < cnt; ++e) {
            if ((s_ck[e] >> 16) == t) {
                float v = s_cv[e]; int kk = s_ck[e] & 0xFFFF;
                if (v > bv || (v == bv && kk < bi)) { bv = v; bi = kk; }
            }
        }
        s_bestv[t] = bv; s_besti[t] = bi;
        argm_out[b0 + t] = (float)bi;
    }
    __syncthreads();

    // ---- Phase D: exp + row sums
    #pragma unroll
    for (int m = 0; m < 4; ++m)
        #pragma unroll
        for (int i = 0; i < 4; ++i) {
            const float bvv = s_bestv[m * 16 + g * 4 + i];
            float s = 0.f;
            #pragma unroll
            for (int ct = 0; ct < 8; ++ct) {
                float e = __expf(ALPHA * (acc[m][ct][i] - bvv));
                acc[m][ct][i] = e;
                s += e;
            }
            #pragma unroll
            for (int off = 8; off >= 1; off >>= 1) s += __shfl_xor(s, off, 64);
            if (q15 == 0) s_sump[wv][m * 16 + g * 4 + i] = s;
        }
    __syncthreads();
    if (t < RB) {
        float s = s_sump[0][t];
        #pragma unroll
        for (int w = 1; w < 8; ++w) s += s_sump[w][t];
        s_den[t] = 1.0f / s;
    }
    __syncthreads();

    // ---- Phase E: soft_assign -> global + pool (bf16) + stats
    float csum[8];
    #pragma unroll
    for (int ct = 0; ct < 8; ++ct) csum[ct] = 0.f;
    #pragma unroll
    for (int m = 0; m < 4; ++m)
        #pragma unroll
        for (int i = 0; i < 4; ++i) {
            const int row = m * 16 + g * 4 + i;
            const float dn = s_den[row];
            float* orow = soft_out + (size_t)(b0 + row) * KCB + wv * 128 + q15;
            us* prow = &pool[(size_t)row * PSTR + wv * 128 + q15];
            #pragma unroll
            for (int ct = 0; ct < 8; ++ct) {
                float sv = acc[m][ct][i] * dn;
                orow[ct * 16] = sv;
                prow[ct * 16] = (us)bf16r(sv);
                csum[ct] += sv;
            }
        }
    #pragma unroll
    for (int ct = 0; ct < 8; ++ct) {
        float v = csum[ct];
        v += __shfl_xor(v, 16, 64);
        v += __shfl_xor(v, 32, 64);
        csum[ct] = v;
    }
    if (use_part) {
        if (lane < 16) {
            #pragma unroll
            for (int ct = 0; ct < 8; ++ct)
                part_ws[(size_t)bid * KCB + wv * 128 + ct * 16 + lane] = csum[ct];
        }
    } else {
        if (lane < 16) {
            #pragma unroll
            for (int ct = 0; ct < 8; ++ct)
                atomicAdd(avg_ws + wv * 128 + ct * 16 + lane, csum[ct]);
        }
    }
    if (t == 0) {
        float cs = 0.f;
        #pragma unroll
        for (int r = 0; r < RB; ++r) cs += s_bestv[r];
        atomicAdd(clu_ws, cs);
    }
    __syncthreads();

    // ---- Phase F: hard_quantized = emb[argmax]
    const float4* emb4 = (const float4*)emb;
    #pragma unroll
    for (int u = 0; u < 16; ++u) {
        int idx = t + u * NT2;
        int r = idx >> 7, c = idx & 127;
        ((float4*)(hq_out + (size_t)(b0 + r) * D))[c] = emb4[(size_t)s_besti[r] * 128 + c];
    }

    // ---- Phase G: quant GEMM
    f32x4 qac[4][4];
    #pragma unroll
    for (int m = 0; m < 4; ++m)
        #pragma unroll
        for (int ct = 0; ct < 4; ++ct) { f32x4 z = {0.f, 0.f, 0.f, 0.f}; qac[m][ct] = z; }

    const us* pBq = embT + (size_t)(wv * 128) * 512 + (size_t)lane * 8;
    #define LDB_Q(ks, ct) (*(const short8v*)(pBq + (size_t)((ct) * 32 + (ks)) * 512))
    #define LDA_Q(row, ks) (*(const short8v*)&pool[(size_t)(row) * PSTR + (ks) * 32 + g * 8])

    short8v qE[4], qO[4];
    #pragma unroll
    for (int ct = 0; ct < 4; ++ct) qE[ct] = LDB_Q(0, ct);
    for (int ks = 0; ks < 32; ks += 2) {
        #pragma unroll
        for (int ct = 0; ct < 4; ++ct) qO[ct] = LDB_Q(ks + 1, ct);
        {
            short8v af0 = LDA_Q(q15, ks), af1 = LDA_Q(16 + q15, ks);
            short8v af2 = LDA_Q(32 + q15, ks), af3 = LDA_Q(48 + q15, ks);
            #pragma unroll
            for (int ct = 0; ct < 4; ++ct) {
                qac[0][ct] = __builtin_amdgcn_mfma_f32_16x16x32_bf16(af0, qE[ct], qac[0][ct], 0, 0, 0);
                qac[1][ct] = __builtin_amdgcn_mfma_f32_16x16x32_bf16(af1, qE[ct], qac[1][ct], 0, 0, 0);
                qac[2][ct] = __builtin_amdgcn_mfma_f32_16x16x32_bf16(af2, qE[ct], qac[2][ct], 0, 0, 0);
                qac[3][ct] = __builtin_amdgcn_mfma_f32_16x16x32_bf16(af3, qE[ct], qac[3][ct], 0, 0, 0);
            }
        }
        const int ksn = (ks + 2 < 32) ? ks + 2 : 0;
        #pragma unroll
        for (int ct = 0; ct < 4; ++ct) qE[ct] = LDB_Q(ksn, ct);
        {
            short8v af0 = LDA_Q(q15, ks + 1), af1 = LDA_Q(16 + q15, ks + 1);
            short8v af2 = LDA_Q(32 + q15, ks + 1), af3 = LDA_Q(48 + q15, ks + 1);
            #pragma unroll
            for (int ct = 0; ct < 4; ++ct) {
                qac[0][ct] = __builtin_amdgcn_mfma_f32_16x16x32_bf16(af0, qO[ct], qac[0][ct], 0, 0, 0);
                qac[1][ct] = __builtin_amdgcn_mfma_f32_16x16x32_bf16(af1, qO[ct], qac[1][ct], 0, 0, 0);
                qac[2][ct] = __builtin_amdgcn_mfma_f32_16x16x32_bf16(af2, qO[ct], qac[2][ct], 0, 0, 0);
                qac[3][ct] = __builtin_amdgcn_mfma_f32_16x16x32_bf16(af3, qO[ct], qac[3][ct], 0, 0, 0);
            }
        }
    }

    // ---- Phase H: q write + fused SSE
    float sse = 0.f;
    #pragma unroll
    for (int m = 0; m < 4; ++m)
        #pragma unroll
        for (int i = 0; i < 4; ++i) {
            const int rloc = m * 16 + g * 4 + i;
            const int row = b0 + rloc;
            const float rv = s_inv[rloc];
            const float* lrow = lat + (size_t)row * D + wv * 64 + q15;
            float* qrow = q_out + (size_t)row * D + wv * 64 + q15;
            #pragma unroll
            for (int ct = 0; ct < 4; ++ct) {
                float qv = qac[m][ct][i];
                qrow[ct * 16] = qv;
                float df = qv - lrow[ct * 16] * rv;
                sse += df * df;
            }
        }
    sse = wave_reduce_sum(sse);
    if (lane == 0) part[wv] = sse;
    __syncthreads();
    if (t == 0) {
        float s = 0.f;
        #pragma unroll
        for (int w = 0; w < 8; ++w) s += part[w];
        atomicAdd(sse_ws, s);
    }
    #undef LDB_A
    #undef LDA_A
    #undef LDB_Q
    #undef LDA_Q

    // ================= Stages R1/R2: reductions + scalars =================
    gbar_arrive(&ctr[1]);
    if (use_part) {
        if (bid < 16) {
            gbar_wait(&ctr[1], nblk);
            for (int c = t; c < KCB; c += NT2) {
                float s = 0.f;
                #pragma unroll
                for (int r = 0; r < 16; ++r) s += part_ws[(size_t)(bid * 16 + r) * KCB + c];
                red_ws[(size_t)bid * KCB + c] = s;
            }
            gbar_arrive(&ctr[2]);
            if (bid == 0) {
                gbar_wait(&ctr[2], 16);
                float ent = 0.f;
                for (int c = t; c < KCB; c += NT2) {
                    float av = 0.f;
                    #pragma unroll
                    for (int j = 0; j < 16; ++j) av += red_ws[(size_t)j * KCB + c];
                    float pv = av * invB;
                    ent -= pv * logf(pv + 1e-10f);
                }
                ent = wave_reduce_sum(ent);
                if (lane == 0) part[wv] = ent;
                __syncthreads();
                if (t == 0) {
                    float e = 0.f;
                    #pragma unroll
                    for (int w = 0; w < 8; ++w) e += part[w];
                    *out_ent = e;
                    *out_vq  = 1.25f * (*sse_ws) * invBD;
                    *out_cm  = (*clu_ws) * invB;
                }
            }
        }
    } else {
        if (bid == 0) {
            gbar_wait(&ctr[1], nblk);
            float ent = 0.f;
            for (int c = t; c < KCB; c += NT2) {
                float pv = avg_ws[c] * invB;
                ent -= pv * logf(pv + 1e-10f);
            }
            ent = wave_reduce_sum(ent);
            if (lane == 0) part[wv] = ent;
            __syncthreads();
            if (t == 0) {
                float e = 0.f;
                #pragma unroll
                for (int w = 0; w < 8; ++w) e += part[w];
                *out_ent = e;
                *out_vq  = 1.25f * (*sse_ws) * invBD;
                *out_cm  = (*clu_ws) * invB;
            }
        }
    }
}

extern "C" void kernel_launch(void* const* d_in, const int* in_sizes, int n_in,
                              void* d_out, int out_size, void* d_ws, size_t ws_size,
                              hipStream_t stream)
{
    const float* lat = (const float*)d_in[0];
    const float* emb = (const float*)d_in[1];
    const int B = in_sizes[0] / D;           // 16384
    float* out = (float*)d_out;

    const size_t vq_off   = (size_t)B * D;
    const size_t ent_off  = vq_off + 1;
    const size_t argm_off = vq_off + 2;
    const size_t hq_off   = argm_off + (size_t)B;
    const size_t soft_off = hq_off + (size_t)B * D;
    const size_t cm_off   = soft_off + (size_t)B * KCB;

    const int nblk = B / RB;                          // 256 blocks == 256 CUs

    us* cb_bf    = (us*)d_ws;                         // 1 MB fragment-major
    us* embT_bf  = cb_bf + (size_t)KCB * D;           // 1 MB fragment-major
    float* cbinv = (float*)(embT_bf + (size_t)D * KCB);   // 4 KB
    float* avg_ws = cbinv + KCB;                      // 4 KB
    float* scal   = avg_ws + KCB;                     // sse, clu, 3 ctrs (32 B)
    float* part_ws = scal + 8;                        // nblk*K floats (1 MB)
    float* red_ws  = part_ws + (size_t)nblk * KCB;    // 16*K floats (64 KB)

    const size_t need = (size_t)((char*)(red_ws + 16 * KCB) - (char*)d_ws);
    const int use_part = (ws_size >= need) ? 1 : 0;

    if (use_part) hipMemsetAsync(scal, 0, 32, stream);
    else          hipMemsetAsync(avg_ws, 0, KCB * 4 + 32, stream);

    const int lds_bytes = RB * PSTR * 2;              // 133,120 B dynamic pool

    k_all<<<nblk, NT2, lds_bytes, stream>>>(lat, emb, cb_bf, embT_bf, cbinv,
                                            avg_ws, scal, part_ws, red_ws, use_part,
                                            out, out + soft_off, out + argm_off, out + hq_off,
                                            out + vq_off, out + ent_off, out + cm_off,
                                            1.0f / (float)B, 1.0f / ((float)B * (float)D), nblk);
}